// Round 1
// baseline (43.157 us; speedup 1.0000x reference)
//
#include <hip/hip_runtime.h>
#include <math.h>

#define BB 64
#define HH 512
#define IN_DIM 256
#define OUT_DIM 256

// One wave (64 lanes) per (b,i) row of hebb.
// lane handles j = lane*4 .. lane*4+3 and j+256 .. j+259 (two float4s = 512 cols).
__global__ __launch_bounds__(256) void fused_row_kernel(
    const float* __restrict__ inputs, const float* __restrict__ prev,
    const float* __restrict__ hebb,   const float* __restrict__ w,
    const float* __restrict__ alpha,  const float* __restrict__ eta,
    const float* __restrict__ Wi,     const float* __restrict__ bi,
    float* __restrict__ hidden, float* __restrict__ hebb_new)
{
    const int wid  = (blockIdx.x * 256 + threadIdx.x) >> 6;  // row id = b*H + i
    const int lane = threadIdx.x & 63;
    const int b = wid >> 9;          // H = 512
    const int i = wid & (HH - 1);

    const size_t row_off = (size_t)wid * HH;
    const float* hrow = hebb  + row_off;
    const float* wrow = w     + (size_t)i * HH;
    const float* arow = alpha + (size_t)i * HH;
    const float* prow = prev  + (size_t)b * HH;

    const int j0 = lane * 4;
    const int j1 = j0 + 256;

    const float4 h0 = *(const float4*)(hrow + j0);
    const float4 h1 = *(const float4*)(hrow + j1);
    const float4 w0 = *(const float4*)(wrow + j0);
    const float4 w1 = *(const float4*)(wrow + j1);
    const float4 a0 = *(const float4*)(arow + j0);
    const float4 a1 = *(const float4*)(arow + j1);
    const float4 p0 = *(const float4*)(prow + j0);
    const float4 p1 = *(const float4*)(prow + j1);

    float acc = 0.f;
    acc += (w0.x + a0.x * h0.x) * p0.x;
    acc += (w0.y + a0.y * h0.y) * p0.y;
    acc += (w0.z + a0.z * h0.z) * p0.z;
    acc += (w0.w + a0.w * h0.w) * p0.w;
    acc += (w1.x + a1.x * h1.x) * p1.x;
    acc += (w1.y + a1.y * h1.y) * p1.y;
    acc += (w1.z + a1.z * h1.z) * p1.z;
    acc += (w1.w + a1.w * h1.w) * p1.w;

    // input projection: IN=256 = 64 lanes * 4
    const float4 wi = *(const float4*)(Wi + (size_t)i * IN_DIM + j0);
    const float4 xv = *(const float4*)(inputs + (size_t)b * IN_DIM + j0);
    acc += wi.x * xv.x + wi.y * xv.y + wi.z * xv.z + wi.w * xv.w;

    // wave-64 butterfly reduce
    acc += __shfl_xor(acc, 32, 64);
    acc += __shfl_xor(acc, 16, 64);
    acc += __shfl_xor(acc,  8, 64);
    acc += __shfl_xor(acc,  4, 64);
    acc += __shfl_xor(acc,  2, 64);
    acc += __shfl_xor(acc,  1, 64);

    const float hval = tanhf(acc + bi[i]);
    if (lane == 0) hidden[wid] = hval;

    const float e = eta[0] * hval;
    float4 o0, o1;
    o0.x = fminf(1.f, fmaxf(-1.f, h0.x + e * p0.x));
    o0.y = fminf(1.f, fmaxf(-1.f, h0.y + e * p0.y));
    o0.z = fminf(1.f, fmaxf(-1.f, h0.z + e * p0.z));
    o0.w = fminf(1.f, fmaxf(-1.f, h0.w + e * p0.w));
    o1.x = fminf(1.f, fmaxf(-1.f, h1.x + e * p1.x));
    o1.y = fminf(1.f, fmaxf(-1.f, h1.y + e * p1.y));
    o1.z = fminf(1.f, fmaxf(-1.f, h1.z + e * p1.z));
    o1.w = fminf(1.f, fmaxf(-1.f, h1.w + e * p1.w));
    *(float4*)(hebb_new + row_off + j0) = o0;
    *(float4*)(hebb_new + row_off + j1) = o1;
}

// One block per batch b: a_out[b,:] (256 dots of length 512) + v_out[b].
__global__ __launch_bounds__(256) void out_proj_kernel(
    const float* __restrict__ hidden, const float* __restrict__ Wo,
    const float* __restrict__ bo,     const float* __restrict__ Wv,
    const float* __restrict__ bv,
    float* __restrict__ a_out, float* __restrict__ v_out)
{
    __shared__ float hs[HH];
    __shared__ float red[256];
    const int b = blockIdx.x;
    const int t = threadIdx.x;

    hs[t]       = hidden[b * HH + t];
    hs[t + 256] = hidden[b * HH + t + 256];
    __syncthreads();

    const float* worow = Wo + (size_t)t * HH;
    float acc = bo[t];
    #pragma unroll 4
    for (int j = 0; j < HH; j += 4) {
        const float4 wv4 = *(const float4*)(worow + j);
        acc += hs[j]     * wv4.x;
        acc += hs[j + 1] * wv4.y;
        acc += hs[j + 2] * wv4.z;
        acc += hs[j + 3] * wv4.w;
    }
    a_out[b * OUT_DIM + t] = acc;

    // v_out: block reduction of hidden . Wv
    float vp = hs[t] * Wv[t] + hs[t + 256] * Wv[t + 256];
    red[t] = vp;
    __syncthreads();
    for (int s = 128; s > 0; s >>= 1) {
        if (t < s) red[t] += red[t + s];
        __syncthreads();
    }
    if (t == 0) v_out[b] = red[0] + bv[0];
}

extern "C" void kernel_launch(void* const* d_in, const int* in_sizes, int n_in,
                              void* d_out, int out_size, void* d_ws, size_t ws_size,
                              hipStream_t stream) {
    const float* inputs = (const float*)d_in[0];
    const float* prev   = (const float*)d_in[1];
    const float* hebb   = (const float*)d_in[2];
    const float* w      = (const float*)d_in[3];
    const float* alpha  = (const float*)d_in[4];
    const float* eta    = (const float*)d_in[5];
    const float* Wi     = (const float*)d_in[6];
    const float* bi     = (const float*)d_in[7];
    const float* Wo     = (const float*)d_in[8];
    const float* bo     = (const float*)d_in[9];
    const float* Wv     = (const float*)d_in[10];
    const float* bv     = (const float*)d_in[11];

    float* out      = (float*)d_out;
    float* a_out    = out;                       // [B, OUT]
    float* v_out    = a_out + BB * OUT_DIM;      // [B, 1]
    float* hidden   = v_out + BB;                // [B, H]
    float* hebb_new = hidden + BB * HH;          // [B, H, H]

    // B*H = 32768 rows, 4 waves (rows) per 256-thread block -> 8192 blocks
    fused_row_kernel<<<dim3(BB * HH / 4), dim3(256), 0, stream>>>(
        inputs, prev, hebb, w, alpha, eta, Wi, bi, hidden, hebb_new);

    out_proj_kernel<<<dim3(BB), dim3(256), 0, stream>>>(
        hidden, Wo, bo, Wv, bv, a_out, v_out);
}

// Round 3
// 39.775 us; speedup vs baseline: 1.0850x; 1.0850x over previous
//
#include <hip/hip_runtime.h>
#include <math.h>

#define BB 64
#define HH 512
#define IN_DIM 256
#define OUT_DIM 256

typedef float f4 __attribute__((ext_vector_type(4)));

// One wave (64 lanes) handles TWO consecutive rows (b, i0) and (b, i0+1) of hebb.
// Lane covers cols j0 = lane*4 .. +3 and j1 = j0+256 .. +3 (512 cols total).
// prev[b,:] and inputs[b,:] loads are shared between the two rows.
__global__ __launch_bounds__(256) void fused_row_kernel(
    const float* __restrict__ inputs, const float* __restrict__ prev,
    const float* __restrict__ hebb,   const float* __restrict__ w,
    const float* __restrict__ alpha,  const float* __restrict__ eta,
    const float* __restrict__ Wi,     const float* __restrict__ bi,
    float* __restrict__ hidden, float* __restrict__ hebb_new)
{
    const int wid2 = (blockIdx.x * 256 + threadIdx.x) >> 6;  // pair id, [0, B*H/2)
    const int lane = threadIdx.x & 63;
    const int b  = wid2 >> 8;            // 256 pairs per batch
    const int i0 = (wid2 & 255) * 2;     // first row index in H
    const int i1 = i0 + 1;

    const size_t rowA = ((size_t)b * HH + i0) * HH;
    const size_t rowB = rowA + HH;

    const int j0 = lane * 4;
    const int j1 = j0 + 256;

    const float* prow = prev + (size_t)b * HH;
    const f4 p0 = *(const f4*)(prow + j0);
    const f4 p1 = *(const f4*)(prow + j1);

    // streaming (read-once) data: non-temporal
    const f4 hA0 = __builtin_nontemporal_load((const f4*)(hebb + rowA + j0));
    const f4 hA1 = __builtin_nontemporal_load((const f4*)(hebb + rowA + j1));
    const f4 hB0 = __builtin_nontemporal_load((const f4*)(hebb + rowB + j0));
    const f4 hB1 = __builtin_nontemporal_load((const f4*)(hebb + rowB + j1));

    const f4 wA0 = *(const f4*)(w + (size_t)i0 * HH + j0);
    const f4 wA1 = *(const f4*)(w + (size_t)i0 * HH + j1);
    const f4 wB0 = *(const f4*)(w + (size_t)i1 * HH + j0);
    const f4 wB1 = *(const f4*)(w + (size_t)i1 * HH + j1);

    const f4 aA0 = *(const f4*)(alpha + (size_t)i0 * HH + j0);
    const f4 aA1 = *(const f4*)(alpha + (size_t)i0 * HH + j1);
    const f4 aB0 = *(const f4*)(alpha + (size_t)i1 * HH + j0);
    const f4 aB1 = *(const f4*)(alpha + (size_t)i1 * HH + j1);

    f4 vA = (wA0 + aA0 * hA0) * p0 + (wA1 + aA1 * hA1) * p1;
    f4 vB = (wB0 + aB0 * hB0) * p0 + (wB1 + aB1 * hB1) * p1;

    // input projection (IN=256 = 64 lanes * 4), inputs load shared
    const f4 xv  = *(const f4*)(inputs + (size_t)b * IN_DIM + j0);
    const f4 wiA = *(const f4*)(Wi + (size_t)i0 * IN_DIM + j0);
    const f4 wiB = *(const f4*)(Wi + (size_t)i1 * IN_DIM + j0);
    vA += wiA * xv;
    vB += wiB * xv;

    float accA = vA.x + vA.y + vA.z + vA.w;
    float accB = vB.x + vB.y + vB.z + vB.w;

    // two interleaved wave-64 butterfly reductions (latency overlaps)
    #pragma unroll
    for (int d = 32; d > 0; d >>= 1) {
        accA += __shfl_xor(accA, d, 64);
        accB += __shfl_xor(accB, d, 64);
    }

    const float hvA = tanhf(accA + bi[i0]);
    const float hvB = tanhf(accB + bi[i1]);
    if (lane == 0) {
        hidden[(size_t)b * HH + i0] = hvA;
        hidden[(size_t)b * HH + i1] = hvB;
    }

    const float et = eta[0];
    const float eA = et * hvA;
    const float eB = et * hvB;

    f4 o;
    o = hA0 + eA * p0;
    o = __builtin_elementwise_min(__builtin_elementwise_max(o, (f4)(-1.f)), (f4)(1.f));
    __builtin_nontemporal_store(o, (f4*)(hebb_new + rowA + j0));
    o = hA1 + eA * p1;
    o = __builtin_elementwise_min(__builtin_elementwise_max(o, (f4)(-1.f)), (f4)(1.f));
    __builtin_nontemporal_store(o, (f4*)(hebb_new + rowA + j1));
    o = hB0 + eB * p0;
    o = __builtin_elementwise_min(__builtin_elementwise_max(o, (f4)(-1.f)), (f4)(1.f));
    __builtin_nontemporal_store(o, (f4*)(hebb_new + rowB + j0));
    o = hB1 + eB * p1;
    o = __builtin_elementwise_min(__builtin_elementwise_max(o, (f4)(-1.f)), (f4)(1.f));
    __builtin_nontemporal_store(o, (f4*)(hebb_new + rowB + j1));
}

// One wave per output element: o in [0,256) -> a_out[b,o]; o==256 -> v_out[b].
__global__ __launch_bounds__(256) void out_proj_kernel(
    const float* __restrict__ hidden, const float* __restrict__ Wo,
    const float* __restrict__ bo,     const float* __restrict__ Wv,
    const float* __restrict__ bv,
    float* __restrict__ a_out, float* __restrict__ v_out)
{
    const int wid  = (blockIdx.x * 256 + threadIdx.x) >> 6;  // [0, 64*257)
    const int lane = threadIdx.x & 63;
    const int b = wid / 257;
    const int o = wid - b * 257;

    const int j0 = lane * 4;
    const int j1 = j0 + 256;

    const float* hrow = hidden + (size_t)b * HH;
    const f4 h0 = *(const f4*)(hrow + j0);
    const f4 h1 = *(const f4*)(hrow + j1);

    const float* wrow = (o < OUT_DIM) ? (Wo + (size_t)o * HH) : Wv;
    const f4 w0 = *(const f4*)(wrow + j0);
    const f4 w1 = *(const f4*)(wrow + j1);

    const f4 pv = h0 * w0 + h1 * w1;
    float acc = pv.x + pv.y + pv.z + pv.w;

    #pragma unroll
    for (int d = 32; d > 0; d >>= 1) acc += __shfl_xor(acc, d, 64);

    if (lane == 0) {
        if (o < OUT_DIM) a_out[(size_t)b * OUT_DIM + o] = acc + bo[o];
        else             v_out[b] = acc + bv[0];
    }
}

extern "C" void kernel_launch(void* const* d_in, const int* in_sizes, int n_in,
                              void* d_out, int out_size, void* d_ws, size_t ws_size,
                              hipStream_t stream) {
    const float* inputs = (const float*)d_in[0];
    const float* prev   = (const float*)d_in[1];
    const float* hebb   = (const float*)d_in[2];
    const float* w      = (const float*)d_in[3];
    const float* alpha  = (const float*)d_in[4];
    const float* eta    = (const float*)d_in[5];
    const float* Wi     = (const float*)d_in[6];
    const float* bi     = (const float*)d_in[7];
    const float* Wo     = (const float*)d_in[8];
    const float* bo     = (const float*)d_in[9];
    const float* Wv     = (const float*)d_in[10];
    const float* bv     = (const float*)d_in[11];

    float* out      = (float*)d_out;
    float* a_out    = out;                       // [B, OUT]
    float* v_out    = a_out + BB * OUT_DIM;      // [B, 1]
    float* hidden   = v_out + BB;                // [B, H]
    float* hebb_new = hidden + BB * HH;          // [B, H, H]

    // B*H/2 = 16384 row-pairs, 4 waves per 256-thread block -> 4096 blocks
    fused_row_kernel<<<dim3(BB * HH / 2 / 4), dim3(256), 0, stream>>>(
        inputs, prev, hebb, w, alpha, eta, Wi, bi, hidden, hebb_new);

    // 64 * 257 = 16448 waves -> 4112 blocks of 4 waves
    out_proj_kernel<<<dim3((BB * 257 + 3) / 4), dim3(256), 0, stream>>>(
        hidden, Wo, bo, Wv, bv, a_out, v_out);
}